// Round 8
// baseline (1036.873 us; speedup 1.0000x reference)
//
#include <hip/hip_runtime.h>
#include <stdint.h>
#include <math.h>

#define NB      8
#define NPTS    16384
#define NPOINT  512
#define NCH     128
#define KNBR    32
#define R2      0.04f

#define FPS_THR 512                  // threads per block (8 waves), all roles
#define PPT     32                   // chunks per wave (each chunk = 64 pts)
#define QBLKS   512                  // query blocks (8 waves = 8 centroids ea)

// ws layout
#define CENT_OFF 0                   // 8*512*4 = 16 KB (memset to -1 pre-launch)
#define MAP_OFF  16384               // 8*16384*4 = 512 KB sorted->orig map

// argmax step over (value desc, index asc) using DPP permute (VALU latency)
#define DPP_ARG_STEP(v, p, CTRL) do {                                          \
    float _ov = __builtin_bit_cast(float, __builtin_amdgcn_update_dpp(         \
        __builtin_bit_cast(int, (v)), __builtin_bit_cast(int, (v)),            \
        (CTRL), 0xF, 0xF, false));                                             \
    int _op = __builtin_amdgcn_update_dpp((p), (p), (CTRL), 0xF, 0xF, false);  \
    bool _t = (_ov > (v)) || ((_ov == (v)) && (_op < (p)));                    \
    (v) = _t ? _ov : (v);                                                      \
    (p) = _t ? _op : (p);                                                      \
} while (0)

// 8x8x8 morton cell id (9 bits) for a point in [0,1)^3
__device__ __forceinline__ int cell_of(float x, float y, float z) {
    int cx = (int)(x * 8.0f); cx = cx < 0 ? 0 : (cx > 7 ? 7 : cx);
    int cy = (int)(y * 8.0f); cy = cy < 0 ? 0 : (cy > 7 ? 7 : cy);
    int cz = (int)(z * 8.0f); cz = cz < 0 ? 0 : (cz > 7 ? 7 : cz);
    int m = 0;
    m |= ((cx & 1) << 2) | ((cx & 2) << 4) | ((cx & 4) << 6);
    m |= ((cy & 1) << 1) | ((cy & 2) << 3) | ((cy & 4) << 5);
    m |=  (cz & 1)       | ((cz & 2) << 2) | ((cz & 4) << 4);
    return m;
}

// -------- fused kernel ------------------------------------------------------
// blocks [0,8):    FPS, one CU per batch (round-7 structure, unchanged).
//                  cent[] entries published progressively via device-scope
//                  atomic stores (value IS the payload; relaxed suffices).
// blocks [8,520):  query+pool. Each WAVE owns one centroid (b,s): polls
//                  cent[b*512+s] (>=0 means ready; -1 sentinel memset by
//                  host), then ball-builds from xyz and max-pools DIRECTLY
//                  from feat (B,128,N) — the scattered gather is L3-resident
//                  (feat = 64 MB < 256 MB LLC) and runs in FPS's shadow.
//                  No transpose pass, no inter-wave barrier anywhere.
__global__
__attribute__((amdgpu_flat_work_group_size(FPS_THR, FPS_THR)))
__attribute__((amdgpu_waves_per_eu(2, 4)))
void fps_query_kernel(const float* __restrict__ xyz,
                      const float* __restrict__ feat,
                      float* __restrict__ out,     // new_xyz at [0,12288)
                      int* __restrict__ cent,      // ws: 8*512 ints (-1 init)
                      int* __restrict__ map,       // ws: 8*16384 ints
                      float* __restrict__ out_sub) // (B,128,512)
{
    const int blk = blockIdx.x;
    const int tid = threadIdx.x;
    const int lane = tid & 63;
    const int wid  = tid >> 6;

    if (blk < NB) {
        // ================= FPS role (round-7 verified structure) ===========
        const int b = blk;
        const float* xb = xyz + (size_t)b * NPTS * 3;
        int* gmap = map + b * NPTS;

        __shared__ int   s_hist[512];
        __shared__ float s_meta[8][PPT][4];
        __shared__ float s_v[2][8];
        __shared__ int   s_p[2][8];

        // ---- 1. histogram ----
        s_hist[tid] = 0;
        __syncthreads();
        for (int k = 0; k < PPT; ++k) {
            int p = k * FPS_THR + tid;
            int c = cell_of(xb[p * 3 + 0], xb[p * 3 + 1], xb[p * 3 + 2]);
            atomicAdd(&s_hist[c], 1);
        }
        __syncthreads();
        // ---- 2. inclusive scan (Hillis-Steele, in place) ----
        int mycount = s_hist[tid];
        for (int off = 1; off < 512; off <<= 1) {
            int v = (tid >= off) ? s_hist[tid - off] : 0;
            __syncthreads();
            s_hist[tid] += v;
            __syncthreads();
        }
        int excl = s_hist[tid] - mycount;
        __syncthreads();
        s_hist[tid] = excl;           // running scatter offsets
        __syncthreads();
        // ---- 3. scatter sorted->orig map to global ws ----
        for (int k = 0; k < PPT; ++k) {
            int p = k * FPS_THR + tid;
            int c = cell_of(xb[p * 3 + 0], xb[p * 3 + 1], xb[p * 3 + 2]);
            int pos = atomicAdd(&s_hist[c], 1);
            gmap[pos] = p;
        }
        __threadfence_block();
        __syncthreads();
        // ---- 4. gather sorted coords + orig idx into registers ----
        // INTERLEAVED: slot k of wave wid = global sorted chunk (k*8 + wid)
        float px[PPT], py[PPT], pz[PPT], d[PPT];
        int   idx[PPT];
#pragma unroll
        for (int k = 0; k < PPT; ++k) {
            int pos = (k * 8 + wid) * 64 + lane;
            int op  = gmap[pos];
            idx[k] = op;
            px[k] = xb[op * 3 + 0];
            py[k] = xb[op * 3 + 1];
            pz[k] = xb[op * 3 + 2];
            d[k]  = 1e10f;
        }
        // ---- 5. per-chunk bounding spheres ----
#pragma unroll
        for (int k = 0; k < PPT; ++k) {
            float mnx = px[k], mxx = px[k];
            float mny = py[k], mxy = py[k];
            float mnz = pz[k], mxz = pz[k];
#pragma unroll
            for (int s = 1; s < 64; s <<= 1) {
                mnx = fminf(mnx, __shfl_xor(mnx, s, 64));
                mxx = fmaxf(mxx, __shfl_xor(mxx, s, 64));
                mny = fminf(mny, __shfl_xor(mny, s, 64));
                mxy = fmaxf(mxy, __shfl_xor(mxy, s, 64));
                mnz = fminf(mnz, __shfl_xor(mnz, s, 64));
                mxz = fmaxf(mxz, __shfl_xor(mxz, s, 64));
            }
            if (lane == 0) {
                float hx = (mxx - mnx) * 0.5f;
                float hy = (mxy - mny) * 0.5f;
                float hz = (mxz - mnz) * 0.5f;
                s_meta[wid][k][0] = (mnx + mxx) * 0.5f;
                s_meta[wid][k][1] = (mny + mxy) * 0.5f;
                s_meta[wid][k][2] = (mnz + mxz) * 0.5f;
                s_meta[wid][k][3] =
                    sqrtf(hx * hx + hy * hy + hz * hz) * 1.0001f + 1e-6f;
            }
        }
        __syncthreads();
        const float bmx = s_meta[wid][lane & 31][0];
        const float bmy = s_meta[wid][lane & 31][1];
        const float bmz = s_meta[wid][lane & 31][2];
        const float br  = s_meta[wid][lane & 31][3];
        float U = 1e10f;

        float cx = xb[0], cy = xb[1], cz = xb[2];
        if (tid == 0) {
            out[((size_t)b * NPOINT + 0) * 3 + 0] = cx;
            out[((size_t)b * NPOINT + 0) * 3 + 1] = cy;
            out[((size_t)b * NPOINT + 0) * 3 + 2] = cz;
            __hip_atomic_store(&cent[b * NPOINT + 0], 0,
                               __ATOMIC_RELAXED, __HIP_MEMORY_SCOPE_AGENT);
        }

        // ---- 6. main loop ----
        for (int i = 1; i < NPOINT; ++i) {
            float dcx = cx - bmx, dcy = cy - bmy, dcz = cz - bmz;
            float dc  = sqrtf(dcx * dcx + dcy * dcy + dcz * dcz);
            float t   = dc - br;
            bool skip = (t > 0.0f) && (t * t >= U + 2e-5f);
            unsigned mask = (unsigned)__ballot(skip);

            if (mask != 0xFFFFFFFFu) {
#pragma unroll
                for (int k = 0; k < PPT; ++k) {
                    if (!(mask & (1u << k))) {   // wave-uniform s_cbranch
                        float dx = __fsub_rn(px[k], cx);
                        float dy = __fsub_rn(py[k], cy);
                        float dz = __fsub_rn(pz[k], cz);
                        float dd = __fadd_rn(__fadd_rn(__fmul_rn(dx, dx),
                                                       __fmul_rn(dy, dy)),
                                             __fmul_rn(dz, dz));
                        d[k] = fminf(d[k], dd);   // np.minimum, exact
                    }
                }
            }
            if (!((mask >> (lane & 31)) & 1u)) {
                float ub = dc + br;
                U = fminf(U, ub * ub * 1.0001f + 1e-6f);
            }
            float vmax = d[0];
#pragma unroll
            for (int k = 1; k < PPT; ++k) vmax = fmaxf(vmax, d[k]);
            int bi = idx[PPT - 1];
#pragma unroll
            for (int k = PPT - 2; k >= 0; --k) bi = (d[k] == vmax) ? idx[k] : bi;

            float rv = vmax;
            int   rp = bi;
            DPP_ARG_STEP(rv, rp, 0xB1);    // xor 1
            DPP_ARG_STEP(rv, rp, 0x4E);    // xor 2
            DPP_ARG_STEP(rv, rp, 0x141);   // row_half_mirror
            DPP_ARG_STEP(rv, rp, 0x140);   // row_mirror
            DPP_ARG_STEP(rv, rp, 0x142);   // row_bcast15
            DPP_ARG_STEP(rv, rp, 0x143);   // row_bcast31
            const int par = i & 1;
            if (lane == 63) { s_v[par][wid] = rv; s_p[par][wid] = rp; }
            __syncthreads();              // the ONLY barrier per iteration
            float fv = s_v[par][lane & 7];
            int   fp = s_p[par][lane & 7];
            DPP_ARG_STEP(fv, fp, 0xB1);
            DPP_ARG_STEP(fv, fp, 0x4E);
            DPP_ARG_STEP(fv, fp, 0x141);
            const int cur = __builtin_amdgcn_readfirstlane(fp);
            cx = xb[cur * 3 + 0];
            cy = xb[cur * 3 + 1];
            cz = xb[cur * 3 + 2];
            if (tid == 0) {
                size_t o = ((size_t)b * NPOINT + i) * 3;
                out[o + 0] = cx; out[o + 1] = cy; out[o + 2] = cz;
                __hip_atomic_store(&cent[b * NPOINT + i], cur,
                                   __ATOMIC_RELAXED, __HIP_MEMORY_SCOPE_AGENT);
            }
        }
    } else {
        // ================= query + pool role (one centroid per wave) =======
        __shared__ int lidx[8][KNBR];
        const int wv = (blk - NB) * 8 + wid;    // 0..4095
        const int b  = wv >> 9;
        const int s  = wv & 511;
        const float* xb = xyz + (size_t)b * NPTS * 3;

        // poll this centroid's index (value-carrying atomic; -1 = not ready)
        int ci;
        for (;;) {
            ci = __hip_atomic_load(&cent[b * NPOINT + s],
                                   __ATOMIC_RELAXED, __HIP_MEMORY_SCOPE_AGENT);
            if (ci >= 0) break;
            __builtin_amdgcn_s_sleep(8);
        }

        const float sx = xb[ci * 3 + 0];
        const float sy = xb[ci * 3 + 1];
        const float sz = xb[ci * 3 + 2];
        const float snorm = __fadd_rn(__fadd_rn(__fmul_rn(sx, sx),
                                                __fmul_rn(sy, sy)),
                                      __fmul_rn(sz, sz));

        int found = 0;
        for (int base = 0; base < NPTS && found < KNBR; base += 64) {
            int j = base + lane;
            float dx = xb[j * 3 + 0];
            float dy = xb[j * 3 + 1];
            float dz = xb[j * 3 + 2];
            float dn = __fadd_rn(__fadd_rn(__fmul_rn(dx, dx),
                                           __fmul_rn(dy, dy)),
                                 __fmul_rn(dz, dz));
            float dot = __fadd_rn(__fadd_rn(__fmul_rn(sx, dx),
                                            __fmul_rn(sy, dy)),
                                  __fmul_rn(sz, dz));
            // reference order: d = -2*dot; d += snorm; d += dnorm
            float dqp = __fadd_rn(__fadd_rn(__fmul_rn(-2.0f, dot), snorm), dn);
            bool inball = !(dqp > R2);
            unsigned long long m = __ballot(inball);
            int before = (int)__popcll(m & ((1ULL << lane) - 1ULL));
            int slot = found + before;
            if (inball && slot < KNBR) lidx[wid][slot] = j;
            found += (int)__popcll(m);
        }
        int cnt = found < KNBR ? found : KNBR;   // cnt >= 1 (self in ball)
        // no barrier: lidx row is per-wave; compiler orders ds via lgkmcnt

        float a0 = -INFINITY, a1 = -INFINITY;
        const float* fb = feat + (size_t)b * NCH * NPTS;
        for (int m = 0; m < cnt; ++m) {
            int i = lidx[wid][m];
            a0 = fmaxf(a0, fb[(size_t)lane * NPTS + i]);
            a1 = fmaxf(a1, fb[(size_t)(lane + 64) * NPTS + i]);
        }
        out_sub[((size_t)b * NCH + lane) * NPOINT + s] = a0;
        out_sub[((size_t)b * NCH + lane + 64) * NPOINT + s] = a1;
    }
}

extern "C" void kernel_launch(void* const* d_in, const int* in_sizes, int n_in,
                              void* d_out, int out_size, void* d_ws, size_t ws_size,
                              hipStream_t stream)
{
    const float* xyz  = (const float*)d_in[0];   // (8,16384,3)
    const float* feat = (const float*)d_in[1];   // (8,128,16384)
    float* out = (float*)d_out;                  // [new_xyz | sub_features]

    int* cent = (int*)((char*)d_ws + CENT_OFF);
    int* map  = (int*)((char*)d_ws + MAP_OFF);

    // sentinel-init cent to -1 (stream-ordered, graph-capture-safe)
    hipMemsetAsync((char*)d_ws + CENT_OFF, 0xFF, NB * NPOINT * 4, stream);

    hipLaunchKernelGGL(fps_query_kernel, dim3(NB + QBLKS), dim3(FPS_THR), 0,
                       stream, xyz, feat, out, cent, map,
                       out + (size_t)NB * NPOINT * 3);
}